// Round 7
// baseline (249.671 us; speedup 1.0000x reference)
//
#include <hip/hip_runtime.h>
#include <math.h>

#define SEQ_LENGTH 4096
#define D_MODEL   2048
#define BATCH     32
#define TABLE_F4  (SEQ_LENGTH * D_MODEL / 4)   // 2^21 float4s per batch copy
#define TOTAL_F4  (BATCH * TABLE_F4)           // 2^26 float4s total
#define GRID      2048                          // blocks; stride = 2^19 f4 = 8 MiB
#define STRIDE_F4 (GRID * 256)                  // 2^19
#define NITER     (TOTAL_F4 / STRIDE_F4)        // 128

typedef float f4 __attribute__((ext_vector_type(4)));

// Output [B, S, D]: pe[s,2i] = sin(s * 10000^(-2i/D)), pe[s,2i+1] = cos(...),
// broadcast over B.
//
// fillBuffer-shaped grid-stride: at any instant the whole chip writes ONE
// contiguous 8 MiB window that marches forward (R6 showed write BW is
// monotone in frontier compactness: 256MB->4.55, 64MB->5.45 TB/s).
// With stride 2^19 f4, each thread's jj is loop-invariant and s cycles over
// exactly 4 values -> precompute 4 float4s, store loop is PURE stores.
__global__ __launch_bounds__(256) void PositionalEncoding_54915451847173_kernel(
    float* __restrict__ out) {
    const int base = blockIdx.x * 256 + threadIdx.x;   // f4 index, < 2^19
    const int jj   = base & (D_MODEL / 4 - 1);         // float4 within row
    const int s0   = base >> 9;                        // 0..1023

    const float c      = -(2.0f / (float)D_MODEL) * 13.28771237954945f; // -2/D*log2(1e4)
    const float inv2pi = 0.15915494309189535f;
    // NOTE: direct exp2 for both pairs — an f0*ratio recurrence loses 5.5e-6
    // relative freq accuracy -> 0.023 absmax at s=4095 (R5 failure).
    const float w0 = __builtin_amdgcn_exp2f(c * (float)(2 * jj)) * inv2pi;
    const float w1 = __builtin_amdgcn_exp2f(c * (float)(2 * jj + 1)) * inv2pi;

    f4 v[4];                                  // s = s0 + 1024*q, q=0..3 (all < 4096)
    #pragma unroll
    for (int q = 0; q < 4; ++q) {
        const float pos = (float)(s0 + 1024 * q);
        const float r0 = __builtin_amdgcn_fractf(pos * w0);  // revolutions in [0,1)
        const float r1 = __builtin_amdgcn_fractf(pos * w1);
        f4 t;
        t.x = __builtin_amdgcn_sinf(r0);
        t.y = __builtin_amdgcn_cosf(r0);
        t.z = __builtin_amdgcn_sinf(r1);
        t.w = __builtin_amdgcn_cosf(r1);
        v[q] = t;
    }

    // Pure store loop. s-phase repeats with period 4; keep v-index
    // compile-time constant (runtime-indexed ext_vector arrays spill).
    f4* p = (f4*)out + base;
    #pragma unroll 1
    for (int m = 0; m < NITER / 4; ++m) {     // 32 outer iterations
        *p = v[0]; p += STRIDE_F4;
        *p = v[1]; p += STRIDE_F4;
        *p = v[2]; p += STRIDE_F4;
        *p = v[3]; p += STRIDE_F4;
    }
}

extern "C" void kernel_launch(void* const* d_in, const int* in_sizes, int n_in,
                              void* d_out, int out_size, void* d_ws, size_t ws_size,
                              hipStream_t stream) {
    (void)d_in; (void)in_sizes; (void)n_in; (void)d_ws; (void)ws_size; (void)out_size;
    float* out = (float*)d_out;
    PositionalEncoding_54915451847173_kernel<<<GRID, 256, 0, stream>>>(out);
}

// Round 8
// 175.977 us; speedup vs baseline: 1.4188x; 1.4188x over previous
//
#include <hip/hip_runtime.h>
#include <math.h>

#define SEQ_LENGTH 4096
#define D_MODEL   2048
#define BATCH     32
#define TABLE_F4  (SEQ_LENGTH * D_MODEL / 4)   // 2^21 float4s per batch copy
#define TOTAL_F4  (BATCH * TABLE_F4)           // 2^26 float4s total
#define IT        8                            // float4s per thread
#define NWG       (TOTAL_F4 / (256 * IT))      // 32768 blocks (divisible by 8)

typedef float f4 __attribute__((ext_vector_type(4)));

// Output [B, S, D]: pe[s,2i] = sin(s * 10000^(-2i/D)), pe[s,2i+1] = cos(...),
// broadcast over B. R6 structure (block = contiguous 32 KiB, short-lived
// blocks — beats persistent grid-stride, R7 showed drift kills page
// locality) + T1 XCD-bijective swizzle: blocks on XCD k (bid%8==k) cover
// contiguous region k, so each XCD L2's writeback stream is long+sequential.
//
// NOTE: direct exp2 for both pairs — an f0*ratio recurrence loses 5.5e-6
// relative freq accuracy -> 0.023 absmax at s=4095 (R5 failure).
__global__ __launch_bounds__(256) void PositionalEncoding_54915451847173_kernel(
    float* __restrict__ out) {
    // XCD-aware bijective remap: consecutive blockIdx round-robin across the
    // 8 XCDs; remap so each XCD owns one contiguous 1/8 of the output.
    const int bid  = blockIdx.x;
    const int swz  = (bid & 7) * (NWG >> 3) + (bid >> 3);
    const int base = swz * (256 * IT) + threadIdx.x;

    const float c      = -(2.0f / (float)D_MODEL) * 13.28771237954945f; // -2/D*log2(1e4)
    const float inv2pi = 0.15915494309189535f;

    #pragma unroll
    for (int it = 0; it < IT; ++it) {
        const int u  = base + it * 256;         // f4 index in output
        const int t  = u & (TABLE_F4 - 1);      // index within the [S,D] table
        const int jj = t & (D_MODEL / 4 - 1);   // float4 within row, 0..511
        const int s  = t >> 9;                  // seq position (D/4 = 512)

        const float pos = (float)s;
        const float f0 = __builtin_amdgcn_exp2f(c * (float)(2 * jj));
        const float f1 = __builtin_amdgcn_exp2f(c * (float)(2 * jj + 1));

        // v_sin/v_cos take REVOLUTIONS; explicit v_fract range reduction.
        const float r0 = __builtin_amdgcn_fractf(pos * (f0 * inv2pi));
        const float r1 = __builtin_amdgcn_fractf(pos * (f1 * inv2pi));

        f4 v;
        v.x = __builtin_amdgcn_sinf(r0);
        v.y = __builtin_amdgcn_cosf(r0);
        v.z = __builtin_amdgcn_sinf(r1);
        v.w = __builtin_amdgcn_cosf(r1);

        ((f4*)out)[u] = v;
    }
}

extern "C" void kernel_launch(void* const* d_in, const int* in_sizes, int n_in,
                              void* d_out, int out_size, void* d_ws, size_t ws_size,
                              hipStream_t stream) {
    (void)d_in; (void)in_sizes; (void)n_in; (void)d_ws; (void)ws_size; (void)out_size;
    float* out = (float*)d_out;
    PositionalEncoding_54915451847173_kernel<<<NWG, 256, 0, stream>>>(out);
}